// Round 3
// baseline (467.199 us; speedup 1.0000x reference)
//
#include <hip/hip_runtime.h>
#include <math.h>

typedef __bf16 bf16;
typedef __bf16 bf16x4 __attribute__((ext_vector_type(4)));
typedef __bf16 bf16x8 __attribute__((ext_vector_type(8)));
typedef float f32x4 __attribute__((ext_vector_type(4)));

#define AS1 __attribute__((address_space(1)))
#define AS3 __attribute__((address_space(3)))

__device__ __forceinline__ void gload_lds16(const bf16* g, bf16* l) {
    __builtin_amdgcn_global_load_lds((const AS1 void*)g, (AS3 void*)l, 16, 0, 0);
}

// ---------------- weight transpose + cast: src fp32 [K][N] -> dst bf16 [N][K]
__global__ __launch_bounds__(256)
void wprep(const float* __restrict__ src, bf16* __restrict__ dst, int K, int N)
{
    const int idx = blockIdx.x * 256 + threadIdx.x;
    if (idx >= K * N) return;
    const int k = idx / N, n = idx % N;
    dst[(long)n * K + k] = (bf16)src[idx];
}

// ---------------- LN1 + cyclic shift(-4,-4) + window partition -> xw bf16 [B*64win][64][256]
__global__ __launch_bounds__(256)
void ln1_window(const float* __restrict__ x, const float* __restrict__ g,
                const float* __restrict__ be, bf16* __restrict__ xw)
{
    const int t = threadIdx.x;
    const int lane = t & 63;
    const int w = t >> 6;
    const long tok = (long)blockIdx.x * 4 + w;
    const float4 v = ((const float4*)(x + tok * 256))[lane];
    float sum = v.x + v.y + v.z + v.w;
    float sq  = v.x * v.x + v.y * v.y + v.z * v.z + v.w * v.w;
#pragma unroll
    for (int m = 32; m >= 1; m >>= 1) {
        sum += __shfl_xor(sum, m, 64);
        sq  += __shfl_xor(sq,  m, 64);
    }
    const float mean = sum * (1.0f / 256.0f);
    const float var  = sq * (1.0f / 256.0f) - mean * mean;
    const float rstd = rsqrtf(var + 1e-5f);
    const float4 gv = ((const float4*)g)[lane];
    const float4 bv = ((const float4*)be)[lane];
    bf16x4 ov;
    ov[0] = (bf16)((v.x - mean) * rstd * gv.x + bv.x);
    ov[1] = (bf16)((v.y - mean) * rstd * gv.y + bv.y);
    ov[2] = (bf16)((v.z - mean) * rstd * gv.z + bv.z);
    ov[3] = (bf16)((v.w - mean) * rstd * gv.w + bv.w);
    const int b = (int)(tok >> 12);
    const int l = (int)(tok & 4095);
    const int i = l >> 6, j = l & 63;
    const int ip = (i + 60) & 63, jp = (j + 60) & 63;   // shifted coords
    const int winl = ((ip >> 3) << 3) + (jp >> 3);
    const int n = ((ip & 7) << 3) + (jp & 7);
    const long drow = ((long)b * 64 + winl) * 64 + n;
    *(bf16x4*)(xw + drow * 256 + lane * 4) = ov;
}

// ---------------- LN2: y = x + proj_out, then layernorm -> xn2 bf16
__global__ __launch_bounds__(256)
void ln2_kernel(const float* __restrict__ x, const bf16* __restrict__ pj,
                const float* __restrict__ g, const float* __restrict__ be,
                bf16* __restrict__ xn2)
{
    const int t = threadIdx.x;
    const int lane = t & 63;
    const int w = t >> 6;
    const long tok = (long)blockIdx.x * 4 + w;
    const float4 xv = ((const float4*)(x + tok * 256))[lane];
    const bf16x4 pv = *(const bf16x4*)(pj + tok * 256 + lane * 4);
    float y0 = xv.x + (float)pv[0];
    float y1 = xv.y + (float)pv[1];
    float y2 = xv.z + (float)pv[2];
    float y3 = xv.w + (float)pv[3];
    float sum = y0 + y1 + y2 + y3;
    float sq  = y0 * y0 + y1 * y1 + y2 * y2 + y3 * y3;
#pragma unroll
    for (int m = 32; m >= 1; m >>= 1) {
        sum += __shfl_xor(sum, m, 64);
        sq  += __shfl_xor(sq,  m, 64);
    }
    const float mean = sum * (1.0f / 256.0f);
    const float var  = sq * (1.0f / 256.0f) - mean * mean;
    const float rstd = rsqrtf(var + 1e-5f);
    const float4 gv = ((const float4*)g)[lane];
    const float4 bv = ((const float4*)be)[lane];
    bf16x4 ov;
    ov[0] = (bf16)((y0 - mean) * rstd * gv.x + bv.x);
    ov[1] = (bf16)((y1 - mean) * rstd * gv.y + bv.y);
    ov[2] = (bf16)((y2 - mean) * rstd * gv.z + bv.z);
    ov[3] = (bf16)((y3 - mean) * rstd * gv.w + bv.w);
    *(bf16x4*)(xn2 + tok * 256 + lane * 4) = ov;
}

// ---------------- GEMM 256x256 tile, 8 waves, BK=32, double-buffered LDS.
// LDS layout (per tile, per matrix): 256 rows x 32 k, stored as 128 row-pairs
// x 8 slots of 16B; logical slot (par*4 + kchunk) stored at slot ^ (pair&7).
// Staged via global_load_lds (linear dest) with the XOR applied to the
// GLOBAL source address (rule: both-sides-or-neither).
// EPI 0: +bias -> bf16 out[row*N+col]           (QKV)
// EPI 1: +bias -> bf16 out[unwindowed tok*256]  (proj, window-reverse + roll(+4))
// EPI 2: +bias, exact GELU -> bf16 out          (FC1)
// EPI 3: +bias + x residual -> f32 out          (FC2)
template<int EPI>
__global__ __launch_bounds__(512, 2)
void gemm256(const bf16* __restrict__ A, const bf16* __restrict__ Bt,
             const float* __restrict__ bias, void* __restrict__ outp,
             int N, int K, const float* __restrict__ xres)
{
    __shared__ bf16 sA[2][8192];
    __shared__ bf16 sB[2][8192];
    const int t = threadIdx.x;
    const int l = t & 63;
    const int w = t >> 6;
    const int wr = w >> 2, wc = w & 3;
    const long m0 = (long)blockIdx.y * 256;
    const long n0 = (long)blockIdx.x * 256;

    // staging source element-offsets (swizzle baked into global src)
    long asrc[2], bsrc[2];
    int dst_e[2];
#pragma unroll
    for (int j = 0; j < 2; j++) {
        const int idx = j * 512 + t;          // 16B chunk id, 0..1023
        const int p = idx >> 3, s = idx & 7;
        const int sl = s ^ (p & 7);           // logical slot
        const int row = 2 * p + (sl >> 2);
        const int ce = (sl & 3) * 8;          // k element offset
        asrc[j] = (m0 + row) * (long)K + ce;
        bsrc[j] = (n0 + row) * (long)K + ce;
        dst_e[j] = idx * 8;                   // linear LDS element offset
    }

    f32x4 acc[8][4];
#pragma unroll
    for (int i = 0; i < 8; i++)
#pragma unroll
        for (int j = 0; j < 4; j++) acc[i][j] = (f32x4){0.f, 0.f, 0.f, 0.f};

    const int KT = K >> 5;
    const int c = l >> 4;                     // k-chunk 0..3
    const int ra = wr * 128 + (l & 15);
    const int rb = wc * 64 + (l & 15);

    // prologue: stage tile 0 into buf 0
#pragma unroll
    for (int j = 0; j < 2; j++) {
        gload_lds16(A + asrc[j], &sA[0][dst_e[j]]);
        gload_lds16(Bt + bsrc[j], &sB[0][dst_e[j]]);
    }
    __syncthreads();

    for (int kt = 0; kt < KT; ++kt) {
        const int b = kt & 1;
        if (kt + 1 < KT) {
            const long ko = (long)(kt + 1) * 32;
            const int nb = b ^ 1;
#pragma unroll
            for (int j = 0; j < 2; j++) {
                gload_lds16(A + asrc[j] + ko, &sA[nb][dst_e[j]]);
                gload_lds16(Bt + bsrc[j] + ko, &sB[nb][dst_e[j]]);
            }
        }
        bf16x8 bv[4];
#pragma unroll
        for (int ni = 0; ni < 4; ni++) {
            const int row = rb + ni * 16;
            const int ch = ((row >> 1) << 3) + ((((row & 1) << 2) + c) ^ ((row >> 1) & 7));
            bv[ni] = *(const bf16x8*)&sB[b][ch * 8];
        }
#pragma unroll
        for (int mi = 0; mi < 8; mi++) {
            const int row = ra + mi * 16;
            const int ch = ((row >> 1) << 3) + ((((row & 1) << 2) + c) ^ ((row >> 1) & 7));
            const bf16x8 av = *(const bf16x8*)&sA[b][ch * 8];
#pragma unroll
            for (int ni = 0; ni < 4; ni++)
                acc[mi][ni] = __builtin_amdgcn_mfma_f32_16x16x32_bf16(av, bv[ni], acc[mi][ni], 0, 0, 0);
        }
        __syncthreads();
    }

#pragma unroll
    for (int mi = 0; mi < 8; mi++)
#pragma unroll
        for (int ni = 0; ni < 4; ni++)
#pragma unroll
            for (int r = 0; r < 4; r++) {
                const long row = m0 + wr * 128 + mi * 16 + (l >> 4) * 4 + r;
                const int col = (int)(n0 + wc * 64 + ni * 16 + (l & 15));
                float v = acc[mi][ni][r] + bias[col];
                if constexpr (EPI == 0) {
                    ((bf16*)outp)[row * N + col] = (bf16)v;
                } else if constexpr (EPI == 1) {
                    const int gwin = (int)(row >> 6);
                    const int n = (int)(row & 63);
                    const int bb = gwin >> 6, wi = gwin & 63;
                    const int ipp = ((wi >> 3) << 3) + (n >> 3);
                    const int jpp = ((wi & 7) << 3) + (n & 7);
                    const int ii = (ipp + 4) & 63, jj = (jpp + 4) & 63;
                    const long tok = ((long)bb << 12) + (ii << 6) + jj;
                    ((bf16*)outp)[tok * 256 + col] = (bf16)v;
                } else if constexpr (EPI == 2) {
                    const float gl = 0.5f * v * (1.0f + erff(v * 0.70710678118654752f));
                    ((bf16*)outp)[row * N + col] = (bf16)gl;
                } else {
                    ((float*)outp)[row * N + col] = v + xres[row * N + col];
                }
            }
    (void)xres;
}

// ---------------- per-window attention: 1 block = 1 window, wave w does heads {w, w+4}
__global__ __launch_bounds__(256, 2)
void attn_kernel(const bf16* __restrict__ qkv, const float* __restrict__ rpb,
                 bf16* __restrict__ out)
{
    __shared__ bf16 P_lds[4][64 * 64];
    const int t = threadIdx.x;
    const int lane = t & 63;
    const int w = t >> 6;
    const int win = blockIdx.x;          // 0..1023 = b*64 + wi
    const int wi = win & 63;
    const int lr = lane & 15;
    const int lg = lane >> 4;
    const int lk = lg * 8;
    const long base = (long)win * 64 * 768;
    const float scale = 0.17677669529663687f;   // 32^-0.5
    const int whb = (wi >> 3) << 3;             // shifted-image block bases
    const int wwb = (wi & 7) << 3;
    const f32x4 z4 = {0.f, 0.f, 0.f, 0.f};

    for (int hh = 0; hh < 2; hh++) {
        const int head = w + hh * 4;
        const bf16* qp = qkv + base + head * 32;
        const bf16* kp = qkv + base + 256 + head * 32;
        const bf16* vp = qkv + base + 512 + head * 32;

        bf16x8 aq[4], bk[4];
#pragma unroll
        for (int mi = 0; mi < 4; mi++)
            aq[mi] = *(const bf16x8*)(qp + (mi * 16 + lr) * 768 + lk);
#pragma unroll
        for (int ni = 0; ni < 4; ni++)
            bk[ni] = *(const bf16x8*)(kp + (ni * 16 + lr) * 768 + lk);

        f32x4 s[4][4];
#pragma unroll
        for (int i = 0; i < 4; i++)
#pragma unroll
            for (int j = 0; j < 4; j++) s[i][j] = z4;
#pragma unroll
        for (int mi = 0; mi < 4; mi++)
#pragma unroll
            for (int ni = 0; ni < 4; ni++)
                s[mi][ni] = __builtin_amdgcn_mfma_f32_16x16x32_bf16(aq[mi], bk[ni], s[mi][ni], 0, 0, 0);

        // bias + mask + softmax (row n held by 16 lanes sharing lg, 4 col-tiles each)
#pragma unroll
        for (int mi = 0; mi < 4; mi++)
#pragma unroll
            for (int r = 0; r < 4; r++) {
                const int n = mi * 16 + lg * 4 + r;
                const int gi = whb + (n >> 3);
                const int gj = wwb + (n & 7);
                const int idn = (gi < 56 ? 0 : (gi < 60 ? 1 : 2)) * 3 + (gj < 56 ? 0 : (gj < 60 ? 1 : 2));
                float vals[4];
                float rowmax = -3.0e38f;
#pragma unroll
                for (int ni = 0; ni < 4; ni++) {
                    const int m = ni * 16 + lr;
                    const int gi2 = whb + (m >> 3);
                    const int gj2 = wwb + (m & 7);
                    const int idm = (gi2 < 56 ? 0 : (gi2 < 60 ? 1 : 2)) * 3 + (gj2 < 56 ? 0 : (gj2 < 60 ? 1 : 2));
                    const int dj = (n & 7) - (m & 7);
                    const int di = (n >> 3) - (m >> 3);
                    float sv = s[mi][ni][r] * scale + rpb[((dj + 7) * 15 + (di + 7)) * 8 + head];
                    if (idn == idm) sv -= 100.0f;   // faithful to source: -100 where EQUAL
                    vals[ni] = sv;
                    rowmax = fmaxf(rowmax, sv);
                }
#pragma unroll
                for (int msk = 8; msk >= 1; msk >>= 1)
                    rowmax = fmaxf(rowmax, __shfl_xor(rowmax, msk, 64));
                float rsum = 0.f;
#pragma unroll
                for (int ni = 0; ni < 4; ni++) {
                    const float p = __expf(vals[ni] - rowmax);
                    vals[ni] = p;
                    rsum += p;
                }
#pragma unroll
                for (int msk = 8; msk >= 1; msk >>= 1)
                    rsum += __shfl_xor(rsum, msk, 64);
                const float inv = 1.0f / rsum;
#pragma unroll
                for (int ni = 0; ni < 4; ni++)
                    P_lds[w][n * 64 + ni * 16 + lr] = (bf16)(vals[ni] * inv);
            }

        // PV: O[n][d] = sum_key P[n][key] V[key][d]
        f32x4 o[4][2];
#pragma unroll
        for (int i = 0; i < 4; i++)
#pragma unroll
            for (int j = 0; j < 2; j++) o[i][j] = z4;
#pragma unroll
        for (int kk = 0; kk < 2; kk++) {
            bf16x8 bv[2];
#pragma unroll
            for (int ni = 0; ni < 2; ni++)
#pragma unroll
                for (int i = 0; i < 8; i++)
                    bv[ni][i] = vp[(kk * 32 + lk + i) * 768 + ni * 16 + lr];
#pragma unroll
            for (int mi = 0; mi < 4; mi++) {
                const bf16x8 ap = *(const bf16x8*)&P_lds[w][(mi * 16 + lr) * 64 + kk * 32 + lk];
#pragma unroll
                for (int ni = 0; ni < 2; ni++)
                    o[mi][ni] = __builtin_amdgcn_mfma_f32_16x16x32_bf16(ap, bv[ni], o[mi][ni], 0, 0, 0);
            }
        }
        // store: out[(win*64+n)*256 + head*32 + d]
#pragma unroll
        for (int mi = 0; mi < 4; mi++)
#pragma unroll
            for (int ni = 0; ni < 2; ni++)
#pragma unroll
                for (int r = 0; r < 4; r++) {
                    const int n = mi * 16 + lg * 4 + r;
                    const int d = ni * 16 + lr;
                    out[((long)(win * 64 + n)) * 256 + head * 32 + d] = (bf16)o[mi][ni][r];
                }
    }
}

extern "C" void kernel_launch(void* const* d_in, const int* in_sizes, int n_in,
                              void* d_out, int out_size, void* d_ws, size_t ws_size,
                              hipStream_t stream)
{
    (void)in_sizes; (void)n_in; (void)out_size;
    const float* x      = (const float*)d_in[0];
    const float* n1g    = (const float*)d_in[1];
    const float* n1b    = (const float*)d_in[2];
    const float* qkv_w  = (const float*)d_in[3];
    const float* qkv_b  = (const float*)d_in[4];
    const float* rpb    = (const float*)d_in[5];
    const float* proj_w = (const float*)d_in[6];
    const float* proj_b = (const float*)d_in[7];
    const float* n2g    = (const float*)d_in[8];
    const float* n2b    = (const float*)d_in[9];
    const float* fc1_w  = (const float*)d_in[10];
    const float* fc1_b  = (const float*)d_in[11];
    const float* fc2_w  = (const float*)d_in[12];
    const float* fc2_b  = (const float*)d_in[13];
    float* out = (float*)d_out;

    // workspace plan (total 136,314,880 B = 130 MB):
    //   0        .. 2 MB   : transposed bf16 weights
    //   2 MB     .. 34 MB  : xw  -> later attn_o -> later part of hbuf
    //   34 MB    .. 130 MB : qkvb -> later proj_o (first 32MB) -> part of hbuf
    //   xn2 staged in d_out (first 32 MB as bf16; dead before FC2 writes)
    char* ws = (char*)d_ws;
    bf16* qkv_wt  = (bf16*)(ws + 0);          // 768x256
    bf16* proj_wt = (bf16*)(ws + 393216);     // 256x256
    bf16* fc1_wt  = (bf16*)(ws + 524288);     // 1024x256
    bf16* fc2_wt  = (bf16*)(ws + 1048576);    // 256x1024
    bf16* xw      = (bf16*)(ws + 2097152);    // 32MB  [65536][256]
    bf16* qkvb    = (bf16*)(ws + 35651584);   // 96MB  [65536][768]
    bf16* attn_o  = xw;                       // reuse xw (dead after QKV gemm)
    bf16* proj_o  = qkvb;                     // reuse qkvb (dead after attn), 32MB
    bf16* xn2     = (bf16*)d_out;             // stage LN2 output in d_out
    bf16* hbuf    = xw;                       // 128MB over 2..130MB
    if (ws_size < 136314880ull) return;       // insufficient scratch

    wprep<<<768, 256, 0, stream>>>(qkv_w, qkv_wt, 256, 768);
    wprep<<<256, 256, 0, stream>>>(proj_w, proj_wt, 256, 256);
    wprep<<<1024, 256, 0, stream>>>(fc1_w, fc1_wt, 256, 1024);
    wprep<<<1024, 256, 0, stream>>>(fc2_w, fc2_wt, 1024, 256);

    ln1_window<<<16384, 256, 0, stream>>>(x, n1g, n1b, xw);
    gemm256<0><<<dim3(3, 256), 512, 0, stream>>>(xw, qkv_wt, qkv_b, qkvb, 768, 256, nullptr);
    attn_kernel<<<1024, 256, 0, stream>>>(qkvb, rpb, attn_o);
    gemm256<1><<<dim3(1, 256), 512, 0, stream>>>(attn_o, proj_wt, proj_b, proj_o, 256, 256, nullptr);
    ln2_kernel<<<16384, 256, 0, stream>>>(x, proj_o, n2g, n2b, xn2);
    gemm256<2><<<dim3(4, 256), 512, 0, stream>>>(xn2, fc1_wt, fc1_b, hbuf, 1024, 256, nullptr);
    gemm256<3><<<dim3(1, 256), 512, 0, stream>>>(hbuf, fc2_wt, fc2_b, out, 256, 1024, x);
}

// Round 4
// 335.679 us; speedup vs baseline: 1.3918x; 1.3918x over previous
//
#include <hip/hip_runtime.h>
#include <math.h>

typedef __bf16 bf16;
typedef __bf16 bf16x4 __attribute__((ext_vector_type(4)));
typedef __bf16 bf16x8 __attribute__((ext_vector_type(8)));
typedef float f32x4 __attribute__((ext_vector_type(4)));

#define AS1 __attribute__((address_space(1)))
#define AS3 __attribute__((address_space(3)))

__device__ __forceinline__ void gload_lds16(const bf16* g, bf16* l) {
    __builtin_amdgcn_global_load_lds((const AS1 void*)g, (AS3 void*)l, 16, 0, 0);
}

// ---------------- weight transpose + cast: src fp32 [K][N] -> dst bf16 [N][K]
__global__ __launch_bounds__(256)
void wprep(const float* __restrict__ src, bf16* __restrict__ dst, int K, int N)
{
    const int idx = blockIdx.x * 256 + threadIdx.x;
    if (idx >= K * N) return;
    const int k = idx / N, n = idx % N;
    dst[(long)n * K + k] = (bf16)src[idx];
}

// ---------------- LN1 + cyclic shift(-4,-4) + window partition -> xw bf16 [B*64win][64][256]
__global__ __launch_bounds__(256)
void ln1_window(const float* __restrict__ x, const float* __restrict__ g,
                const float* __restrict__ be, bf16* __restrict__ xw)
{
    const int t = threadIdx.x;
    const int lane = t & 63;
    const int w = t >> 6;
    const long tok = (long)blockIdx.x * 4 + w;
    const float4 v = ((const float4*)(x + tok * 256))[lane];
    float sum = v.x + v.y + v.z + v.w;
    float sq  = v.x * v.x + v.y * v.y + v.z * v.z + v.w * v.w;
#pragma unroll
    for (int m = 32; m >= 1; m >>= 1) {
        sum += __shfl_xor(sum, m, 64);
        sq  += __shfl_xor(sq,  m, 64);
    }
    const float mean = sum * (1.0f / 256.0f);
    const float var  = sq * (1.0f / 256.0f) - mean * mean;
    const float rstd = rsqrtf(var + 1e-5f);
    const float4 gv = ((const float4*)g)[lane];
    const float4 bv = ((const float4*)be)[lane];
    bf16x4 ov;
    ov[0] = (bf16)((v.x - mean) * rstd * gv.x + bv.x);
    ov[1] = (bf16)((v.y - mean) * rstd * gv.y + bv.y);
    ov[2] = (bf16)((v.z - mean) * rstd * gv.z + bv.z);
    ov[3] = (bf16)((v.w - mean) * rstd * gv.w + bv.w);
    const int b = (int)(tok >> 12);
    const int l = (int)(tok & 4095);
    const int i = l >> 6, j = l & 63;
    const int ip = (i + 60) & 63, jp = (j + 60) & 63;   // shifted coords
    const int winl = ((ip >> 3) << 3) + (jp >> 3);
    const int n = ((ip & 7) << 3) + (jp & 7);
    const long drow = ((long)b * 64 + winl) * 64 + n;
    *(bf16x4*)(xw + drow * 256 + lane * 4) = ov;
}

// ---------------- LN2: y = x + proj_out, then layernorm -> xn2 bf16
__global__ __launch_bounds__(256)
void ln2_kernel(const float* __restrict__ x, const bf16* __restrict__ pj,
                const float* __restrict__ g, const float* __restrict__ be,
                bf16* __restrict__ xn2)
{
    const int t = threadIdx.x;
    const int lane = t & 63;
    const int w = t >> 6;
    const long tok = (long)blockIdx.x * 4 + w;
    const float4 xv = ((const float4*)(x + tok * 256))[lane];
    const bf16x4 pv = *(const bf16x4*)(pj + tok * 256 + lane * 4);
    float y0 = xv.x + (float)pv[0];
    float y1 = xv.y + (float)pv[1];
    float y2 = xv.z + (float)pv[2];
    float y3 = xv.w + (float)pv[3];
    float sum = y0 + y1 + y2 + y3;
    float sq  = y0 * y0 + y1 * y1 + y2 * y2 + y3 * y3;
#pragma unroll
    for (int m = 32; m >= 1; m >>= 1) {
        sum += __shfl_xor(sum, m, 64);
        sq  += __shfl_xor(sq,  m, 64);
    }
    const float mean = sum * (1.0f / 256.0f);
    const float var  = sq * (1.0f / 256.0f) - mean * mean;
    const float rstd = rsqrtf(var + 1e-5f);
    const float4 gv = ((const float4*)g)[lane];
    const float4 bv = ((const float4*)be)[lane];
    bf16x4 ov;
    ov[0] = (bf16)((y0 - mean) * rstd * gv.x + bv.x);
    ov[1] = (bf16)((y1 - mean) * rstd * gv.y + bv.y);
    ov[2] = (bf16)((y2 - mean) * rstd * gv.z + bv.z);
    ov[3] = (bf16)((y3 - mean) * rstd * gv.w + bv.w);
    *(bf16x4*)(xn2 + tok * 256 + lane * 4) = ov;
}

// ---------------- GEMM 128x128 tile, 4 waves, BK=32, 3-stage pipelined LDS,
// counted vmcnt (never 0 in main loop), XOR-swizzled LDS (verified R3: 0 conflicts),
// XCD-chunked block remap (nb % 8 == 0 for all our grids).
// LDS per tile per matrix: 128 rows x 32 k as 64 row-pairs x 8 slots of 16B;
// logical slot (row&1)*4+kchunk stored at slot ^ (pair&7); swizzle applied to
// GLOBAL source (linear global_load_lds dest), inverse on ds_read.
// EPI 0: +bias -> bf16 out[row*N+col]           (QKV)
// EPI 1: +bias -> bf16 out[unwindowed tok*256]  (proj, window-reverse + roll(+4))
// EPI 2: +bias, exact GELU -> bf16 out          (FC1)
// EPI 3: +bias + x residual -> f32 out          (FC2)
template<int EPI>
__global__ __launch_bounds__(256, 2)
void gemm_p3(const bf16* __restrict__ A, const bf16* __restrict__ Bt,
             const float* __restrict__ bias, void* __restrict__ outp,
             int N, int K, const float* __restrict__ xres, int gx, int nb)
{
    __shared__ bf16 sA[3][4096];
    __shared__ bf16 sB[3][4096];
    const int t = threadIdx.x;
    const int l = t & 63;
    const int w = t >> 6;
    const int wr = w >> 1, wc = w & 1;
    // XCD-chunked bijective remap: consecutive remapped ids land on one XCD
    const int q = nb >> 3;
    const int id = ((int)blockIdx.x & 7) * q + ((int)blockIdx.x >> 3);
    const long m0 = (long)(id / gx) * 128;
    const long n0 = (long)(id % gx) * 128;

    // staging: 512 16B-chunks per matrix, 2 per thread per matrix (4 loads total)
    long asrc[2], bsrc[2];
    int dst_e[2];
#pragma unroll
    for (int j = 0; j < 2; j++) {
        const int idx = j * 256 + t;          // chunk id 0..511
        const int p = idx >> 3, s = idx & 7;
        const int sl = s ^ (p & 7);           // logical slot
        const int row = 2 * p + (sl >> 2);
        const int ce = (sl & 3) * 8;          // k element offset
        asrc[j] = (m0 + row) * (long)K + ce;
        bsrc[j] = (n0 + row) * (long)K + ce;
        dst_e[j] = idx * 8;                   // linear LDS element offset
    }

    f32x4 acc[4][4];
#pragma unroll
    for (int i = 0; i < 4; i++)
#pragma unroll
        for (int j = 0; j < 4; j++) acc[i][j] = (f32x4){0.f, 0.f, 0.f, 0.f};

    const int KT = K >> 5;
    const int c = l >> 4;                     // k-chunk 0..3
    const int ra = wr * 64 + (l & 15);
    const int rb = wc * 64 + (l & 15);

#define STAGE(bufi, ko)                                                        \
    do {                                                                       \
        _Pragma("unroll")                                                      \
        for (int j = 0; j < 2; j++) {                                          \
            gload_lds16(A + asrc[j] + (ko), &sA[bufi][dst_e[j]]);              \
            gload_lds16(Bt + bsrc[j] + (ko), &sB[bufi][dst_e[j]]);             \
        }                                                                      \
    } while (0)

#define COMPUTE(bufi)                                                          \
    do {                                                                       \
        bf16x8 av[4], bv[4];                                                   \
        _Pragma("unroll")                                                      \
        for (int ni = 0; ni < 4; ni++) {                                       \
            const int row = rb + ni * 16;                                      \
            const int p = row >> 1;                                            \
            const int s = (((row & 1) << 2) + c) ^ (p & 7);                    \
            bv[ni] = *(const bf16x8*)&sB[bufi][(p * 8 + s) * 8];               \
        }                                                                      \
        _Pragma("unroll")                                                      \
        for (int mi = 0; mi < 4; mi++) {                                       \
            const int row = ra + mi * 16;                                      \
            const int p = row >> 1;                                            \
            const int s = (((row & 1) << 2) + c) ^ (p & 7);                    \
            av[mi] = *(const bf16x8*)&sA[bufi][(p * 8 + s) * 8];               \
        }                                                                      \
        _Pragma("unroll")                                                      \
        for (int mi = 0; mi < 4; mi++)                                         \
            _Pragma("unroll")                                                  \
            for (int ni = 0; ni < 4; ni++)                                     \
                acc[mi][ni] = __builtin_amdgcn_mfma_f32_16x16x32_bf16(         \
                    av[mi], bv[ni], acc[mi][ni], 0, 0, 0);                     \
    } while (0)

    // prologue: stage tiles 0 and 1
    STAGE(0, 0);
    STAGE(1, 32);

    int buf = 0;
    for (int kt = 0; kt < KT - 1; ++kt) {
        // wait only for tile kt's 4 loads; tile kt+1's 4 stay in flight
        asm volatile("s_waitcnt vmcnt(4)" ::: "memory");
        __builtin_amdgcn_s_barrier();
        __builtin_amdgcn_sched_barrier(0);
        if (kt + 2 < KT) {
            const int nbuf = (buf + 2 >= 3) ? buf - 1 : buf + 2;
            STAGE(nbuf, (long)(kt + 2) * 32);
        }
        COMPUTE(buf);
        buf = (buf + 1 == 3) ? 0 : buf + 1;
    }
    asm volatile("s_waitcnt vmcnt(0)" ::: "memory");
    __builtin_amdgcn_s_barrier();
    __builtin_amdgcn_sched_barrier(0);
    COMPUTE(buf);
#undef STAGE
#undef COMPUTE

#pragma unroll
    for (int mi = 0; mi < 4; mi++)
#pragma unroll
        for (int ni = 0; ni < 4; ni++)
#pragma unroll
            for (int r = 0; r < 4; r++) {
                const long row = m0 + wr * 64 + mi * 16 + (l >> 4) * 4 + r;
                const int col = (int)(n0 + wc * 64 + ni * 16 + (l & 15));
                float v = acc[mi][ni][r] + bias[col];
                if constexpr (EPI == 0) {
                    ((bf16*)outp)[row * N + col] = (bf16)v;
                } else if constexpr (EPI == 1) {
                    const int gwin = (int)(row >> 6);
                    const int n = (int)(row & 63);
                    const int bb = gwin >> 6, wi = gwin & 63;
                    const int ipp = ((wi >> 3) << 3) + (n >> 3);
                    const int jpp = ((wi & 7) << 3) + (n & 7);
                    const int ii = (ipp + 4) & 63, jj = (jpp + 4) & 63;
                    const long tok = ((long)bb << 12) + (ii << 6) + jj;
                    ((bf16*)outp)[tok * 256 + col] = (bf16)v;
                } else if constexpr (EPI == 2) {
                    const float gl = 0.5f * v * (1.0f + erff(v * 0.70710678118654752f));
                    ((bf16*)outp)[row * N + col] = (bf16)gl;
                } else {
                    ((float*)outp)[row * N + col] = v + xres[row * N + col];
                }
            }
    (void)xres;
}

// ---------------- per-window attention: 1 block = 1 window, wave w does heads {w, w+4}
__global__ __launch_bounds__(256, 2)
void attn_kernel(const bf16* __restrict__ qkv, const float* __restrict__ rpb,
                 bf16* __restrict__ out)
{
    __shared__ bf16 P_lds[4][64 * 64];
    const int t = threadIdx.x;
    const int lane = t & 63;
    const int w = t >> 6;
    const int win = blockIdx.x;          // 0..1023 = b*64 + wi
    const int wi = win & 63;
    const int lr = lane & 15;
    const int lg = lane >> 4;
    const int lk = lg * 8;
    const long base = (long)win * 64 * 768;
    const float scale = 0.17677669529663687f;   // 32^-0.5
    const int whb = (wi >> 3) << 3;             // shifted-image block bases
    const int wwb = (wi & 7) << 3;
    const f32x4 z4 = {0.f, 0.f, 0.f, 0.f};

    for (int hh = 0; hh < 2; hh++) {
        const int head = w + hh * 4;
        const bf16* qp = qkv + base + head * 32;
        const bf16* kp = qkv + base + 256 + head * 32;
        const bf16* vp = qkv + base + 512 + head * 32;

        bf16x8 aq[4], bk[4];
#pragma unroll
        for (int mi = 0; mi < 4; mi++)
            aq[mi] = *(const bf16x8*)(qp + (mi * 16 + lr) * 768 + lk);
#pragma unroll
        for (int ni = 0; ni < 4; ni++)
            bk[ni] = *(const bf16x8*)(kp + (ni * 16 + lr) * 768 + lk);

        f32x4 s[4][4];
#pragma unroll
        for (int i = 0; i < 4; i++)
#pragma unroll
            for (int j = 0; j < 4; j++) s[i][j] = z4;
#pragma unroll
        for (int mi = 0; mi < 4; mi++)
#pragma unroll
            for (int ni = 0; ni < 4; ni++)
                s[mi][ni] = __builtin_amdgcn_mfma_f32_16x16x32_bf16(aq[mi], bk[ni], s[mi][ni], 0, 0, 0);

        // bias + mask + softmax (row n held by 16 lanes sharing lg, 4 col-tiles each)
#pragma unroll
        for (int mi = 0; mi < 4; mi++)
#pragma unroll
            for (int r = 0; r < 4; r++) {
                const int n = mi * 16 + lg * 4 + r;
                const int gi = whb + (n >> 3);
                const int gj = wwb + (n & 7);
                const int idn = (gi < 56 ? 0 : (gi < 60 ? 1 : 2)) * 3 + (gj < 56 ? 0 : (gj < 60 ? 1 : 2));
                float vals[4];
                float rowmax = -3.0e38f;
#pragma unroll
                for (int ni = 0; ni < 4; ni++) {
                    const int m = ni * 16 + lr;
                    const int gi2 = whb + (m >> 3);
                    const int gj2 = wwb + (m & 7);
                    const int idm = (gi2 < 56 ? 0 : (gi2 < 60 ? 1 : 2)) * 3 + (gj2 < 56 ? 0 : (gj2 < 60 ? 1 : 2));
                    const int dj = (n & 7) - (m & 7);
                    const int di = (n >> 3) - (m >> 3);
                    float sv = s[mi][ni][r] * scale + rpb[((dj + 7) * 15 + (di + 7)) * 8 + head];
                    if (idn == idm) sv -= 100.0f;   // faithful to source: -100 where EQUAL
                    vals[ni] = sv;
                    rowmax = fmaxf(rowmax, sv);
                }
#pragma unroll
                for (int msk = 8; msk >= 1; msk >>= 1)
                    rowmax = fmaxf(rowmax, __shfl_xor(rowmax, msk, 64));
                float rsum = 0.f;
#pragma unroll
                for (int ni = 0; ni < 4; ni++) {
                    const float p = __expf(vals[ni] - rowmax);
                    vals[ni] = p;
                    rsum += p;
                }
#pragma unroll
                for (int msk = 8; msk >= 1; msk >>= 1)
                    rsum += __shfl_xor(rsum, msk, 64);
                const float inv = 1.0f / rsum;
#pragma unroll
                for (int ni = 0; ni < 4; ni++)
                    P_lds[w][n * 64 + ni * 16 + lr] = (bf16)(vals[ni] * inv);
            }

        // PV: O[n][d] = sum_key P[n][key] V[key][d]
        f32x4 o[4][2];
#pragma unroll
        for (int i = 0; i < 4; i++)
#pragma unroll
            for (int j = 0; j < 2; j++) o[i][j] = z4;
#pragma unroll
        for (int kk = 0; kk < 2; kk++) {
            bf16x8 bv[2];
#pragma unroll
            for (int ni = 0; ni < 2; ni++)
#pragma unroll
                for (int i = 0; i < 8; i++)
                    bv[ni][i] = vp[(kk * 32 + lk + i) * 768 + ni * 16 + lr];
#pragma unroll
            for (int mi = 0; mi < 4; mi++) {
                const bf16x8 ap = *(const bf16x8*)&P_lds[w][(mi * 16 + lr) * 64 + kk * 32 + lk];
#pragma unroll
                for (int ni = 0; ni < 2; ni++)
                    o[mi][ni] = __builtin_amdgcn_mfma_f32_16x16x32_bf16(ap, bv[ni], o[mi][ni], 0, 0, 0);
            }
        }
        // store: out[(win*64+n)*256 + head*32 + d]
#pragma unroll
        for (int mi = 0; mi < 4; mi++)
#pragma unroll
            for (int ni = 0; ni < 2; ni++)
#pragma unroll
                for (int r = 0; r < 4; r++) {
                    const int n = mi * 16 + lg * 4 + r;
                    const int d = ni * 16 + lr;
                    out[((long)(win * 64 + n)) * 256 + head * 32 + d] = (bf16)o[mi][ni][r];
                }
    }
}

extern "C" void kernel_launch(void* const* d_in, const int* in_sizes, int n_in,
                              void* d_out, int out_size, void* d_ws, size_t ws_size,
                              hipStream_t stream)
{
    (void)in_sizes; (void)n_in; (void)out_size;
    const float* x      = (const float*)d_in[0];
    const float* n1g    = (const float*)d_in[1];
    const float* n1b    = (const float*)d_in[2];
    const float* qkv_w  = (const float*)d_in[3];
    const float* qkv_b  = (const float*)d_in[4];
    const float* rpb    = (const float*)d_in[5];
    const float* proj_w = (const float*)d_in[6];
    const float* proj_b = (const float*)d_in[7];
    const float* n2g    = (const float*)d_in[8];
    const float* n2b    = (const float*)d_in[9];
    const float* fc1_w  = (const float*)d_in[10];
    const float* fc1_b  = (const float*)d_in[11];
    const float* fc2_w  = (const float*)d_in[12];
    const float* fc2_b  = (const float*)d_in[13];
    float* out = (float*)d_out;

    // workspace plan (total 136,314,880 B = 130 MB):
    //   0        .. 2 MB   : transposed bf16 weights
    //   2 MB     .. 34 MB  : xw  -> later attn_o -> later part of hbuf
    //   34 MB    .. 130 MB : qkvb -> later proj_o (first 32MB) -> part of hbuf
    //   xn2 staged in d_out (first 32 MB as bf16; dead before FC2 writes)
    char* ws = (char*)d_ws;
    bf16* qkv_wt  = (bf16*)(ws + 0);          // 768x256
    bf16* proj_wt = (bf16*)(ws + 393216);     // 256x256
    bf16* fc1_wt  = (bf16*)(ws + 524288);     // 1024x256
    bf16* fc2_wt  = (bf16*)(ws + 1048576);    // 256x1024
    bf16* xw      = (bf16*)(ws + 2097152);    // 32MB  [65536][256]
    bf16* qkvb    = (bf16*)(ws + 35651584);   // 96MB  [65536][768]
    bf16* attn_o  = xw;                       // reuse xw (dead after QKV gemm)
    bf16* proj_o  = qkvb;                     // reuse qkvb (dead after attn), 32MB
    bf16* xn2     = (bf16*)d_out;             // stage LN2 output in d_out
    bf16* hbuf    = xw;                       // 128MB over 2..130MB
    if (ws_size < 136314880ull) return;       // insufficient scratch

    wprep<<<768, 256, 0, stream>>>(qkv_w, qkv_wt, 256, 768);
    wprep<<<256, 256, 0, stream>>>(proj_w, proj_wt, 256, 256);
    wprep<<<1024, 256, 0, stream>>>(fc1_w, fc1_wt, 256, 1024);
    wprep<<<1024, 256, 0, stream>>>(fc2_w, fc2_wt, 1024, 256);

    ln1_window<<<16384, 256, 0, stream>>>(x, n1g, n1b, xw);
    gemm_p3<0><<<3072, 256, 0, stream>>>(xw, qkv_wt, qkv_b, qkvb, 768, 256, nullptr, 6, 3072);
    attn_kernel<<<1024, 256, 0, stream>>>(qkvb, rpb, attn_o);
    gemm_p3<1><<<1024, 256, 0, stream>>>(attn_o, proj_wt, proj_b, proj_o, 256, 256, nullptr, 2, 1024);
    ln2_kernel<<<16384, 256, 0, stream>>>(x, proj_o, n2g, n2b, xn2);
    gemm_p3<2><<<4096, 256, 0, stream>>>(xn2, fc1_wt, fc1_b, hbuf, 1024, 256, nullptr, 8, 4096);
    gemm_p3<3><<<1024, 256, 0, stream>>>(hbuf, fc2_wt, fc2_b, out, 256, 1024, x, 2, 1024);
}